// Round 3
// baseline (12178.445 us; speedup 1.0000x reference)
//
#include <hip/hip_runtime.h>

// Recurrent spiking LIF network: T=64, B=32, NE=4096, NI=1024, N=5120.
// Spikes are exactly {0,1}; currents are subset-sums of fp32 weights,
// accumulated in fp64 so our trajectory is spike-identical to the fp64
// numpy reference (round-2 verified: absmax 0.0).
//
// Round-3 changes (theory: kill per-FMA converts + LDS traffic):
//  - upd writes spikes as fp64 (sd); mv inner loop is pure v_fma_f64.
//  - spikes read with wave-UNIFORM addresses straight from global
//    (no threadIdx in address) -> compiler can use scalar s_load; no LDS,
//    no __syncthreads, weights cvt once per k (amortized over 32 batches).

#define NE 4096
#define NI 1024
#define NN 5120
#define BB 32

typedef __attribute__((ext_vector_type(4))) double double4v;

// ---------------- matvec partial kernel ----------------
// grid: (NN/256, G), block 256. Each thread owns target neuron n and
// accumulates acc[32] (all batches) over its k-range of KRANGE sources.
template <int KRANGE>
__global__ __launch_bounds__(256) void mv_kernel(
    const float* __restrict__ W_ee, const float* __restrict__ W_ei,
    const float* __restrict__ W_ie, const float* __restrict__ W_ii,
    const double* __restrict__ sd,   // [BB][NN] spikes as fp64 (0.0/1.0)
    double* __restrict__ partial)    // [G][BB][NN]
{
    const int n = blockIdx.x * 256 + threadIdx.x;   // 0..NN-1
    const int kbase = blockIdx.y * KRANGE;

    double acc[BB];
#pragma unroll
    for (int j = 0; j < BB; ++j) acc[j] = 0.0;

    const bool isE = (n < NE);
    const int nr = isE ? n : n - NE;
    const float* __restrict__ rowA = isE ? (W_ee + (size_t)nr * NE) : (W_ei + (size_t)nr * NE);
    const float* __restrict__ rowB = isE ? (W_ie + (size_t)nr * NI) : (W_ii + (size_t)nr * NI);

    // NE % 4 == 0 and k advances by 4, so a quad never straddles the E/I split.
    for (int kk = 0; kk < KRANGE; kk += 4) {
        const int k = kbase + kk;
        const float4 w = (k < NE)
            ? *reinterpret_cast<const float4*>(rowA + k)
            : *reinterpret_cast<const float4*>(rowB + (k - NE));
        const double w0 = (double)w.x, w1 = (double)w.y,
                     w2 = (double)w.z, w3 = (double)w.w;

#pragma unroll
        for (int j = 0; j < BB; ++j) {
            // wave-uniform address: no threadIdx component -> scalar load
            const double4v sp = *reinterpret_cast<const double4v*>(
                sd + (size_t)j * NN + k);
            acc[j] += w0 * sp.x + w1 * sp.y + w2 * sp.z + w3 * sp.w;
        }
    }

#pragma unroll
    for (int j = 0; j < BB; ++j)
        partial[((size_t)blockIdx.y * BB + j) * NN + n] = acc[j];
}

// ---------------- LIF update kernel ----------------
template <int G>
__global__ __launch_bounds__(256) void upd_kernel(
    const float* __restrict__ ext_exc,   // [T][BB][NE]
    const float* __restrict__ ext_inh,   // [T][BB][NI]
    const double* __restrict__ partial,  // [G][BB][NN]
    double* __restrict__ v,              // [BB][NN]
    double* __restrict__ sd,             // [BB][NN] fp64 spikes
    float* __restrict__ out,             // [T][BB][NN]
    int t)
{
    const int idx = blockIdx.x * 256 + threadIdx.x;   // < BB*NN
    const int b = idx / NN;
    const int n = idx - b * NN;

    const float ext = (n < NE)
        ? ext_exc[((size_t)t * BB + b) * NE + n]
        : ext_inh[((size_t)t * BB + b) * NI + (n - NE)];

    double acc = (double)ext;
#pragma unroll
    for (int g = 0; g < G; ++g)
        acc += partial[((size_t)g * BB + b) * NN + n];

    const double vv = v[idx] * 0.9 + acc;
    const double sp = (vv > 1.0) ? 1.0 : 0.0;
    out[(size_t)t * BB * NN + idx] = (float)sp;
    v[idx] = vv * (1.0 - sp);
    sd[idx] = sp;
}

extern "C" void kernel_launch(void* const* d_in, const int* in_sizes, int n_in,
                              void* d_out, int out_size, void* d_ws, size_t ws_size,
                              hipStream_t stream) {
    const float* ext_exc = (const float*)d_in[0];
    const float* ext_inh = (const float*)d_in[1];
    const float* W_ee = (const float*)d_in[2];
    const float* W_ei = (const float*)d_in[3];
    const float* W_ie = (const float*)d_in[4];
    const float* W_ii = (const float*)d_in[5];
    float* out = (float*)d_out;

    const int T = in_sizes[0] / (BB * NE);   // 64

    const size_t SN = (size_t)BB * NN;       // 163840
    double* v = (double*)d_ws;
    double* sd = v + SN;
    double* partial = sd + SN;
    const size_t stateBytes = 2 * SN * sizeof(double);   // v + sd, ~2.6 MB

    // largest k-split G whose fp64 partial fits the workspace
    int G = 32;
    while (G > 1 && stateBytes + (size_t)G * SN * sizeof(double) > ws_size) G >>= 1;

    hipMemsetAsync(d_ws, 0, stateBytes, stream);   // v = 0, spikes = 0

    for (int t = 0; t < T; ++t) {
        switch (G) {
            case 32:
                mv_kernel<160> <<<dim3(NN/256, 32), 256, 0, stream>>>(W_ee, W_ei, W_ie, W_ii, sd, partial);
                upd_kernel<32><<<(int)(SN/256), 256, 0, stream>>>(ext_exc, ext_inh, partial, v, sd, out, t);
                break;
            case 16:
                mv_kernel<320> <<<dim3(NN/256, 16), 256, 0, stream>>>(W_ee, W_ei, W_ie, W_ii, sd, partial);
                upd_kernel<16><<<(int)(SN/256), 256, 0, stream>>>(ext_exc, ext_inh, partial, v, sd, out, t);
                break;
            case 8:
                mv_kernel<640> <<<dim3(NN/256, 8), 256, 0, stream>>>(W_ee, W_ei, W_ie, W_ii, sd, partial);
                upd_kernel<8> <<<(int)(SN/256), 256, 0, stream>>>(ext_exc, ext_inh, partial, v, sd, out, t);
                break;
            case 4:
                mv_kernel<1280><<<dim3(NN/256, 4), 256, 0, stream>>>(W_ee, W_ei, W_ie, W_ii, sd, partial);
                upd_kernel<4> <<<(int)(SN/256), 256, 0, stream>>>(ext_exc, ext_inh, partial, v, sd, out, t);
                break;
            case 2:
                mv_kernel<2560><<<dim3(NN/256, 2), 256, 0, stream>>>(W_ee, W_ei, W_ie, W_ii, sd, partial);
                upd_kernel<2> <<<(int)(SN/256), 256, 0, stream>>>(ext_exc, ext_inh, partial, v, sd, out, t);
                break;
            default:
                mv_kernel<5120><<<dim3(NN/256, 1), 256, 0, stream>>>(W_ee, W_ei, W_ie, W_ii, sd, partial);
                upd_kernel<1> <<<(int)(SN/256), 256, 0, stream>>>(ext_exc, ext_inh, partial, v, sd, out, t);
                break;
        }
    }
}

// Round 5
// 11247.247 us; speedup vs baseline: 1.0828x; 1.0828x over previous
//
#include <hip/hip_runtime.h>

// Recurrent spiking LIF network: T=64, B=32, NE=4096, NI=1024, N=5120.
// Spikes are exactly {0,1}; currents are subset-sums of fp32 weights.
// fp64 accumulation => trajectory spike-identical to the fp64 numpy
// reference (verified round 2: absmax 0.0).
//
// Round-5: back to the PROVEN round-2 VALU structure (fp64 MFMA layout is
// unverifiable here and gives no FLOP advantage: fp64 MFMA == fp64 VALU
// peak on MI355X). Changes vs round 2:
//  - spikes kept as fp64 in global (sd) and staged as fp64 in LDS ->
//    inner loop is PURE v_fma_f64 (no per-FMA v_cvt_f64_f32): ~2x less VALU.
//  - 64-thread blocks, grid (NN/64, G=32) = 2560 blocks = 10/CU exactly
//    (round 2 had 640 blocks = 2.5/CU with 3:2 imbalance).
// LDS reads are wave-uniform broadcasts (round 2 measured 0 conflicts).

#define NE 4096
#define NI 1024
#define NN 5120
#define BB 32
#define CHUNK 80     // k-elements staged per LDS pass: 32*80*8 = 20 KB

typedef double double4_t __attribute__((ext_vector_type(4)));

// ---------------- matvec partial kernel (pure fp64 FMA) ----------------
// grid: (NN/64, G), block 64 (1 wave). Thread owns target neuron n,
// accumulates acc[32] (all batches) over KR = NN/G sources.
template <int KR>
__global__ __launch_bounds__(64) void mv_kernel(
    const float* __restrict__ W_ee, const float* __restrict__ W_ei,
    const float* __restrict__ W_ie, const float* __restrict__ W_ii,
    const double* __restrict__ sd,   // [BB][NN] spikes as fp64 (0.0/1.0)
    double* __restrict__ partial)    // [G][BB][NN]
{
    __shared__ double s_l[BB][CHUNK];
    const int tid = threadIdx.x;
    const int n = blockIdx.x * 64 + tid;       // 0..NN-1
    const int kbase0 = blockIdx.y * KR;

    double acc[BB];
#pragma unroll
    for (int j = 0; j < BB; ++j) acc[j] = 0.0;

    const bool isE = (n < NE);
    const int nr = isE ? n : n - NE;
    const float* __restrict__ rowA = isE ? (W_ee + (size_t)nr * NE) : (W_ei + (size_t)nr * NE);
    const float* __restrict__ rowB = isE ? (W_ie + (size_t)nr * NI) : (W_ii + (size_t)nr * NI);

    for (int c = 0; c < KR / CHUNK; ++c) {
        const int kbase = kbase0 + c * CHUNK;

        if (c) __syncthreads();
        for (int ii = tid; ii < BB * CHUNK; ii += 64) {
            const int j = ii / CHUNK;
            const int kk = ii - j * CHUNK;
            s_l[j][kk] = sd[(size_t)j * NN + kbase + kk];
        }
        __syncthreads();

        int aEnd = NE - kbase;                 // E/I source boundary in chunk
        if (aEnd < 0) aEnd = 0;
        if (aEnd > CHUNK) aEnd = CHUNK;        // always a multiple of 4

        for (int kk = 0; kk < aEnd; kk += 4) {
            const float4 w = *reinterpret_cast<const float4*>(rowA + kbase + kk);
            const double w0 = (double)w.x, w1 = (double)w.y,
                         w2 = (double)w.z, w3 = (double)w.w;
#pragma unroll
            for (int j = 0; j < BB; ++j) {
                const double4_t sv = *reinterpret_cast<const double4_t*>(&s_l[j][kk]);
                acc[j] += w0 * sv.x + w1 * sv.y + w2 * sv.z + w3 * sv.w;
            }
        }
        for (int kk = aEnd; kk < CHUNK; kk += 4) {
            const float4 w = *reinterpret_cast<const float4*>(rowB + (kbase + kk - NE));
            const double w0 = (double)w.x, w1 = (double)w.y,
                         w2 = (double)w.z, w3 = (double)w.w;
#pragma unroll
            for (int j = 0; j < BB; ++j) {
                const double4_t sv = *reinterpret_cast<const double4_t*>(&s_l[j][kk]);
                acc[j] += w0 * sv.x + w1 * sv.y + w2 * sv.z + w3 * sv.w;
            }
        }
    }

#pragma unroll
    for (int j = 0; j < BB; ++j)
        partial[((size_t)blockIdx.y * BB + j) * NN + n] = acc[j];
}

// ---------------- LIF update kernel ----------------
template <int G>
__global__ __launch_bounds__(256) void upd_kernel(
    const float* __restrict__ ext_exc,   // [T][BB][NE]
    const float* __restrict__ ext_inh,   // [T][BB][NI]
    const double* __restrict__ partial,  // [G][BB][NN]
    double* __restrict__ v,              // [BB][NN]
    double* __restrict__ sd,             // [BB][NN] fp64 spikes
    float* __restrict__ out,             // [T][BB][NN]
    int t)
{
    const int idx = blockIdx.x * 256 + threadIdx.x;   // < BB*NN
    const int b = idx / NN;
    const int n = idx - b * NN;

    const float ext = (n < NE)
        ? ext_exc[((size_t)t * BB + b) * NE + n]
        : ext_inh[((size_t)t * BB + b) * NI + (n - NE)];

    double acc = (double)ext;
#pragma unroll
    for (int g = 0; g < G; ++g)
        acc += partial[((size_t)g * BB + b) * NN + n];

    const double vv = v[idx] * 0.9 + acc;
    const double sp = (vv > 1.0) ? 1.0 : 0.0;
    out[(size_t)t * BB * NN + idx] = (float)sp;
    v[idx] = vv * (1.0 - sp);
    sd[idx] = sp;
}

extern "C" void kernel_launch(void* const* d_in, const int* in_sizes, int n_in,
                              void* d_out, int out_size, void* d_ws, size_t ws_size,
                              hipStream_t stream) {
    const float* ext_exc = (const float*)d_in[0];
    const float* ext_inh = (const float*)d_in[1];
    const float* W_ee = (const float*)d_in[2];
    const float* W_ei = (const float*)d_in[3];
    const float* W_ie = (const float*)d_in[4];
    const float* W_ii = (const float*)d_in[5];
    float* out = (float*)d_out;

    const int T = in_sizes[0] / (BB * NE);   // 64

    const size_t SN = (size_t)BB * NN;       // 163840
    double* v = (double*)d_ws;               // [BB][NN]
    double* sd = v + SN;                     // [BB][NN]
    double* partial = sd + SN;               // [G][BB][NN]
    const size_t stateBytes = 2 * SN * sizeof(double);   // ~2.6 MB

    // largest k-split G whose fp64 partial fits the workspace
    int G = 32;
    while (G > 1 && stateBytes + (size_t)G * SN * sizeof(double) > ws_size) G >>= 1;

    hipMemsetAsync(d_ws, 0, stateBytes, stream);   // v = 0, spikes = 0

    for (int t = 0; t < T; ++t) {
        switch (G) {
            case 32:
                mv_kernel<160> <<<dim3(NN/64, 32), 64, 0, stream>>>(W_ee, W_ei, W_ie, W_ii, sd, partial);
                upd_kernel<32><<<(int)(SN/256), 256, 0, stream>>>(ext_exc, ext_inh, partial, v, sd, out, t);
                break;
            case 16:
                mv_kernel<320> <<<dim3(NN/64, 16), 64, 0, stream>>>(W_ee, W_ei, W_ie, W_ii, sd, partial);
                upd_kernel<16><<<(int)(SN/256), 256, 0, stream>>>(ext_exc, ext_inh, partial, v, sd, out, t);
                break;
            case 8:
                mv_kernel<640> <<<dim3(NN/64, 8), 64, 0, stream>>>(W_ee, W_ei, W_ie, W_ii, sd, partial);
                upd_kernel<8> <<<(int)(SN/256), 256, 0, stream>>>(ext_exc, ext_inh, partial, v, sd, out, t);
                break;
            case 4:
                mv_kernel<1280><<<dim3(NN/64, 4), 64, 0, stream>>>(W_ee, W_ei, W_ie, W_ii, sd, partial);
                upd_kernel<4> <<<(int)(SN/256), 256, 0, stream>>>(ext_exc, ext_inh, partial, v, sd, out, t);
                break;
            case 2:
                mv_kernel<2560><<<dim3(NN/64, 2), 64, 0, stream>>>(W_ee, W_ei, W_ie, W_ii, sd, partial);
                upd_kernel<2> <<<(int)(SN/256), 256, 0, stream>>>(ext_exc, ext_inh, partial, v, sd, out, t);
                break;
            default:
                mv_kernel<5120><<<dim3(NN/64, 1), 64, 0, stream>>>(W_ee, W_ei, W_ie, W_ii, sd, partial);
                upd_kernel<1> <<<(int)(SN/256), 256, 0, stream>>>(ext_exc, ext_inh, partial, v, sd, out, t);
                break;
        }
    }
}